// Round 3
// baseline (6083.952 us; speedup 1.0000x reference)
//
#include <hip/hip_runtime.h>
#include <math.h>

#define H 1024
#define SEQ 256
#define VOUT 32000
typedef unsigned long long ull;

__device__ __forceinline__ float sigmoidf_(float x) { return 1.f / (1.f + expf(-x)); }

// ---------------------------------------------------------------------------
// Wait-free dataflow slots: one u64 = (generation << 32) | float_bits.
// Posted with a relaxed agent-scope atomic store (cache-bypassing, coherent
// across XCDs, no cache-maintenance cost). Consumers poll until gen >= target
// and take the payload straight from the poll result — the sync IS the data
// transport. Generations are monotonic, so slot reuse is ABA-free; writes of
// gen g+1 are transitively ordered after all reads of gen g through the
// score->c->h dependency chain (every stage requires ALL slots of the
// previous stage before it can produce).
// ---------------------------------------------------------------------------
__device__ __forceinline__ ull ldq(const ull* p) {
    return __hip_atomic_load(p, __ATOMIC_RELAXED, __HIP_MEMORY_SCOPE_AGENT);
}
__device__ __forceinline__ void stq(ull* p, unsigned gen, float v) {
    ull x = ((ull)gen << 32) | (ull)__float_as_uint(v);
    __hip_atomic_store(p, x, __ATOMIC_RELAXED, __HIP_MEMORY_SCOPE_AGENT);
}
// Poll 4 quads of one slot (4 values produced by the 4 waves of one block).
__device__ __forceinline__ float4 poll4(const ull* q, unsigned tgt) {
    ull v0, v1, v2, v3;
    for (;;) {
        v0 = ldq(q + 0); v1 = ldq(q + 1); v2 = ldq(q + 2); v3 = ldq(q + 3);
        if ((unsigned)(v0 >> 32) >= tgt && (unsigned)(v1 >> 32) >= tgt &&
            (unsigned)(v2 >> 32) >= tgt && (unsigned)(v3 >> 32) >= tgt) break;
    }
    float4 r;
    r.x = __uint_as_float((unsigned)v0); r.y = __uint_as_float((unsigned)v1);
    r.z = __uint_as_float((unsigned)v2); r.w = __uint_as_float((unsigned)v3);
    return r;
}
__device__ __forceinline__ float poll1(const ull* q, unsigned tgt) {
    ull v;
    do { v = ldq(q); } while ((unsigned)(v >> 32) < tgt);
    return __uint_as_float((unsigned)v);
}

__device__ __forceinline__ float wsum(float v) {
#pragma unroll
    for (int m = 32; m > 0; m >>= 1) v += __shfl_xor(v, m);
    return v;
}
__device__ __forceinline__ float wmax(float v) {
#pragma unroll
    for (int m = 32; m > 0; m >>= 1) v = fmaxf(v, __shfl_xor(v, m));
    return v;
}

// ---------------------------------------------------------------------------
__global__ __launch_bounds__(256) void gather_kernel(
    const int* __restrict__ input_ids, const int* __restrict__ target_ids,
    const float* __restrict__ enc_emb, const float* __restrict__ dec_emb,
    float* __restrict__ enc_x, float* __restrict__ dec_e)
{
    int b = blockIdx.x, tid = threadIdx.x;
    if (b < SEQ) {
        int tok = input_ids[b];
        const float4* src = (const float4*)(enc_emb + (size_t)tok * H);
        float4* dst = (float4*)(enc_x + (size_t)b * H);
        dst[tid] = src[tid];
    } else {
        int t = b - SEQ;
        int tok = (t == 0) ? 1 : target_ids[t - 1];
        const float4* src = (const float4*)(dec_emb + (size_t)tok * H);
        float4* dst = (float4*)(dec_e + (size_t)t * H);
        dst[tid] = src[tid];
    }
}

// zero all 6144 slot u64s (gen 0 | 0.0f) — initial encoder h = 0 comes free.
__global__ __launch_bounds__(256) void init_kernel(ull* __restrict__ slots)
{
    slots[blockIdx.x * 256 + threadIdx.x] = 0ULL;
}

// ---------------------------------------------------------------------------
// Generic NT GEMM: C[m,n] = sum_k A[m*lda+offa+k] * B[n*ldb+k] (+ bias[n])
// ---------------------------------------------------------------------------
__global__ __launch_bounds__(256) void gemm_nt_kernel(
    const float* __restrict__ A, const float* __restrict__ B,
    const float* __restrict__ bias, float* __restrict__ C,
    int Kdim, int lda, int offa, int ldb, int ldc)
{
    __shared__ float As[16][68];
    __shared__ float Bs[16][68];
    const int tid = threadIdx.x;
    const int m0 = blockIdx.y * 64;
    const int n0 = blockIdx.x * 64;
    const int tr = (tid >> 4) << 2;
    const int tc = (tid & 15) << 2;
    const int lrow = tid >> 2;
    const int lk = (tid & 3) << 2;
    const float* Ab = A + (size_t)m0 * lda + offa;
    const float* Bb = B + (size_t)n0 * ldb;
    float acc[4][4] = {{0.f,0.f,0.f,0.f},{0.f,0.f,0.f,0.f},{0.f,0.f,0.f,0.f},{0.f,0.f,0.f,0.f}};

    for (int k0 = 0; k0 < Kdim; k0 += 16) {
        float4 av = *(const float4*)(Ab + (size_t)lrow * lda + (k0 + lk));
        float4 bv = *(const float4*)(Bb + (size_t)lrow * ldb + (k0 + lk));
        As[lk + 0][lrow] = av.x; As[lk + 1][lrow] = av.y;
        As[lk + 2][lrow] = av.z; As[lk + 3][lrow] = av.w;
        Bs[lk + 0][lrow] = bv.x; Bs[lk + 1][lrow] = bv.y;
        Bs[lk + 2][lrow] = bv.z; Bs[lk + 3][lrow] = bv.w;
        __syncthreads();
#pragma unroll
        for (int k = 0; k < 16; ++k) {
            float4 a = *(const float4*)(&As[k][tr]);
            float4 b = *(const float4*)(&Bs[k][tc]);
            acc[0][0] = fmaf(a.x, b.x, acc[0][0]);
            acc[0][1] = fmaf(a.x, b.y, acc[0][1]);
            acc[0][2] = fmaf(a.x, b.z, acc[0][2]);
            acc[0][3] = fmaf(a.x, b.w, acc[0][3]);
            acc[1][0] = fmaf(a.y, b.x, acc[1][0]);
            acc[1][1] = fmaf(a.y, b.y, acc[1][1]);
            acc[1][2] = fmaf(a.y, b.z, acc[1][2]);
            acc[1][3] = fmaf(a.y, b.w, acc[1][3]);
            acc[2][0] = fmaf(a.z, b.x, acc[2][0]);
            acc[2][1] = fmaf(a.z, b.y, acc[2][1]);
            acc[2][2] = fmaf(a.z, b.z, acc[2][2]);
            acc[2][3] = fmaf(a.z, b.w, acc[2][3]);
            acc[3][0] = fmaf(a.w, b.x, acc[3][0]);
            acc[3][1] = fmaf(a.w, b.y, acc[3][1]);
            acc[3][2] = fmaf(a.w, b.z, acc[3][2]);
            acc[3][3] = fmaf(a.w, b.w, acc[3][3]);
        }
        __syncthreads();
    }
#pragma unroll
    for (int i = 0; i < 4; ++i) {
#pragma unroll
        for (int j = 0; j < 4; ++j) {
            float v = acc[i][j];
            if (bias) v += bias[n0 + tc + j];
            C[(size_t)(m0 + tr + i) * ldc + (n0 + tc + j)] = v;
        }
    }
}

// ---------------------------------------------------------------------------
// Encoder recurrence: 256 blocks x 256 threads; wave w of block b owns unit
// u = b*4+w. Step t: poll h-slots gen>=t, 3 dots, gates, post h-slots gen t+1.
// No barriers at all.
// ---------------------------------------------------------------------------
__global__ __launch_bounds__(256) void enc_rnn_kernel(
    const float* __restrict__ Wh, const float* __restrict__ bh,
    const float* __restrict__ gi_all,
    ull* __restrict__ h_slots, float* __restrict__ encH)
{
    __shared__ float h_s[H];
    const int tid = threadIdx.x, wave = tid >> 6, lane = tid & 63;
    const int b = blockIdx.x, u = b * 4 + wave;
    const float* wr = Wh + (size_t)u * H;
    const float* wz = Wh + (size_t)(u + H) * H;
    const float* wn = Wh + (size_t)(u + 2 * H) * H;
    const float bhr = bh[u], bhz = bh[H + u], bhn = bh[2 * H + u];

    for (int t = 0; t < SEQ; ++t) {
        // prefetch gi (independent of h) before the poll
        float gir = gi_all[t * 3 * H + u];
        float giz = gi_all[t * 3 * H + H + u];
        float gin = gi_all[t * 3 * H + 2 * H + u];
        float4 hv = poll4(h_slots + tid * 8, (unsigned)t);
        __syncthreads();                    // prior step's h_s readers done
        ((float4*)h_s)[tid] = hv;
        __syncthreads();

        float dr = 0.f, dz = 0.f, dn = 0.f;
#pragma unroll 4
        for (int k = lane; k < H; k += 64) {
            float x = h_s[k];
            dr = fmaf(wr[k], x, dr);
            dz = fmaf(wz[k], x, dz);
            dn = fmaf(wn[k], x, dn);
        }
        dr = wsum(dr); dz = wsum(dz); dn = wsum(dn);
        if (lane == 0) {
            float r = sigmoidf_(gir + dr + bhr);
            float z = sigmoidf_(giz + dz + bhz);
            float n = tanhf(gin + r * (dn + bhn));
            float h2 = (1.f - z) * n + z * h_s[u];
            stq(h_slots + b * 8 + wave, (unsigned)(t + 1), h2);
            encH[(size_t)t * H + u] = h2;
        }
    }
}

// ---------------------------------------------------------------------------
// Decoder recurrence: 3 dataflow exchanges per step (scores, c, h).
// h-slots are shared with the encoder: decoder step t polls h gen >= 256+t
// (t=0 sees the encoder's final hidden state), posts gen 257+t.
// ---------------------------------------------------------------------------
__global__ __launch_bounds__(256) void dec_rnn_kernel(
    const float* __restrict__ attn_W, const float* __restrict__ attn_e,
    const float* __restrict__ M, const float* __restrict__ comb_pre,
    const float* __restrict__ Wi, const float* __restrict__ Wh,
    const float* __restrict__ bi, const float* __restrict__ bh,
    ull* __restrict__ h_slots, ull* __restrict__ score_slots,
    ull* __restrict__ c_slots, float* __restrict__ hs_dec)
{
    __shared__ float h_s[H];
    __shared__ float c_s[H];
    __shared__ float a_s[SEQ];
    __shared__ float red8[8];
    const int tid = threadIdx.x, wave = tid >> 6, lane = tid & 63;
    const int b = blockIdx.x, u = b * 4 + wave;
    const float* arow = attn_W + (size_t)b * (2 * H) + H;
    const float* Mrow = M + (size_t)u * SEQ;
    const float* wir = Wi + (size_t)u * H;
    const float* wiz = Wi + (size_t)(u + H) * H;
    const float* win = Wi + (size_t)(u + 2 * H) * H;
    const float* whr = Wh + (size_t)u * H;
    const float* whz = Wh + (size_t)(u + H) * H;
    const float* whn = Wh + (size_t)(u + 2 * H) * H;
    const float bir = bi[u], biz = bi[H + u], bin = bi[2 * H + u];
    const float bhr = bh[u], bhz = bh[H + u], bhn = bh[2 * H + u];

    for (int t = 0; t < SEQ; ++t) {
        // ---- stage 1: score[b] = attn_e[t,b] + attn_W[b,H:] @ h ----
        float ae = attn_e[t * SEQ + b];           // prefetch before poll
        float4 hv = poll4(h_slots + tid * 8, (unsigned)(256 + t));
        __syncthreads();                          // prior h_s/c_s/a_s readers done
        ((float4*)h_s)[tid] = hv;
        __syncthreads();
        float p = 0.f;
#pragma unroll
        for (int k = tid; k < H; k += 256) p = fmaf(arow[k], h_s[k], p);
        p = wsum(p);
        if (lane == 0) red8[wave] = p;
        __syncthreads();
        if (tid == 0)
            stq(score_slots + b * 8, (unsigned)(t + 1),
                red8[0] + red8[1] + red8[2] + red8[3] + ae);

        // ---- stage 2: softmax + c[u] ----
        float cpre = comb_pre[t * H + u];         // prefetch before poll
        float s = poll1(score_slots + tid * 8, (unsigned)(t + 1));
        float m = wmax(s);
        if (lane == 0) red8[4 + wave] = m;        // disjoint from red8[0..3]
        __syncthreads();
        float mx = fmaxf(fmaxf(red8[4], red8[5]), fmaxf(red8[6], red8[7]));
        float ev = expf(s - mx);
        a_s[tid] = ev;
        float sm = wsum(ev);
        if (lane == 0) red8[wave] = sm;           // safe: tid0 consumed old [0..3]
        __syncthreads();
        float inv = 1.f / (red8[0] + red8[1] + red8[2] + red8[3]);
        float pc = 0.f;
#pragma unroll
        for (int k = lane; k < SEQ; k += 64) pc = fmaf(a_s[k], Mrow[k], pc);
        pc = wsum(pc);
        if (lane == 0)
            stq(c_slots + b * 8 + wave, (unsigned)(t + 1),
                fmaxf(0.f, cpre + pc * inv));

        // ---- stage 3: GRU cell ----
        float4 cv = poll4(c_slots + tid * 8, (unsigned)(t + 1));
        __syncthreads();
        ((float4*)c_s)[tid] = cv;
        __syncthreads();
        float dir = 0.f, diz = 0.f, din = 0.f, dhr = 0.f, dhz = 0.f, dhn = 0.f;
#pragma unroll 2
        for (int k = lane; k < H; k += 64) {
            float cvk = c_s[k], hvk = h_s[k];
            dir = fmaf(wir[k], cvk, dir);
            diz = fmaf(wiz[k], cvk, diz);
            din = fmaf(win[k], cvk, din);
            dhr = fmaf(whr[k], hvk, dhr);
            dhz = fmaf(whz[k], hvk, dhz);
            dhn = fmaf(whn[k], hvk, dhn);
        }
        dir = wsum(dir); diz = wsum(diz); din = wsum(din);
        dhr = wsum(dhr); dhz = wsum(dhz); dhn = wsum(dhn);
        if (lane == 0) {
            float r = sigmoidf_(dir + bir + dhr + bhr);
            float z = sigmoidf_(diz + biz + dhz + bhz);
            float n = tanhf(din + bin + r * (dhn + bhn));
            float h2 = (1.f - z) * n + z * h_s[u];
            stq(h_slots + b * 8 + wave, (unsigned)(257 + t), h2);
            hs_dec[(size_t)t * H + u] = h2;
        }
    }
}

// ---------------------------------------------------------------------------
__global__ __launch_bounds__(256) void nll_kernel(
    const float* __restrict__ logits, const int* __restrict__ target_ids,
    float* __restrict__ nll)
{
    const int t = blockIdx.x, tid = threadIdx.x;
    __shared__ float red[256];
    const float* row = logits + (size_t)t * VOUT;
    float mx = -1e30f;
    for (int i = tid; i < VOUT; i += 256) mx = fmaxf(mx, row[i]);
    red[tid] = mx;
    __syncthreads();
    for (int off = 128; off > 0; off >>= 1) {
        if (tid < off) red[tid] = fmaxf(red[tid], red[tid + off]);
        __syncthreads();
    }
    mx = red[0];
    __syncthreads();
    float s = 0.f;
    for (int i = tid; i < VOUT; i += 256) s += expf(row[i] - mx);
    red[tid] = s;
    __syncthreads();
    for (int off = 128; off > 0; off >>= 1) {
        if (tid < off) red[tid] += red[tid + off];
        __syncthreads();
    }
    if (tid == 0) {
        float lse = mx + logf(red[0]);
        nll[t] = lse - row[target_ids[t]];
    }
}

__global__ __launch_bounds__(256) void sum_kernel(
    const float* __restrict__ nll, float* __restrict__ out)
{
    __shared__ float red[256];
    int tid = threadIdx.x;
    red[tid] = nll[tid];
    __syncthreads();
    for (int off = 128; off > 0; off >>= 1) {
        if (tid < off) red[tid] += red[tid + off];
        __syncthreads();
    }
    if (tid == 0) out[0] = red[0];
}

// ---------------------------------------------------------------------------
extern "C" void kernel_launch(void* const* d_in, const int* in_sizes, int n_in,
                              void* d_out, int out_size, void* d_ws, size_t ws_size,
                              hipStream_t stream)
{
    const int*   input_ids  = (const int*)d_in[0];
    const int*   target_ids = (const int*)d_in[1];
    const float* enc_emb = (const float*)d_in[2];
    const float* enc_Wi  = (const float*)d_in[3];
    const float* enc_Wh  = (const float*)d_in[4];
    const float* enc_bi  = (const float*)d_in[5];
    const float* enc_bh  = (const float*)d_in[6];
    const float* dec_emb = (const float*)d_in[7];
    const float* dec_Wi  = (const float*)d_in[8];
    const float* dec_Wh  = (const float*)d_in[9];
    const float* dec_bi  = (const float*)d_in[10];
    const float* dec_bh  = (const float*)d_in[11];
    const float* attn_W  = (const float*)d_in[12];
    const float* attn_b  = (const float*)d_in[13];
    const float* comb_W  = (const float*)d_in[14];
    const float* comb_b  = (const float*)d_in[15];
    const float* out_W   = (const float*)d_in[16];
    const float* out_b   = (const float*)d_in[17];
    float* out = (float*)d_out;

    // slots first (8B-aligned at ws base): h | c | score, each 256 slots x 8 u64
    ull* h_slots     = (ull*)d_ws;
    ull* c_slots     = h_slots + 2048;
    ull* score_slots = c_slots + 2048;
    float* ws = (float*)(score_slots + 2048);
    float* enc_x    = ws; ws += SEQ * H;
    float* dec_e    = ws; ws += SEQ * H;
    float* enc_gi   = ws; ws += SEQ * 3 * H;
    float* attn_e   = ws; ws += SEQ * SEQ;
    float* comb_pre = ws; ws += SEQ * H;
    float* Mmat     = ws; ws += H * SEQ;
    float* encH     = ws; ws += SEQ * H;
    float* hs_dec   = ws; ws += SEQ * H;
    float* nll      = ws; ws += SEQ;
    ws += (256 - ((ws - (float*)d_ws) & 255)) & 255;
    float* logits   = ws; ws += (size_t)SEQ * VOUT;

    // phase 0: gathers + zero slots
    hipLaunchKernelGGL(gather_kernel, dim3(512), dim3(256), 0, stream,
                       input_ids, target_ids, enc_emb, dec_emb, enc_x, dec_e);
    hipLaunchKernelGGL(init_kernel, dim3(24), dim3(256), 0, stream, h_slots);

    // phase 1: batched pre-GEMMs
    hipLaunchKernelGGL(gemm_nt_kernel, dim3(3 * H / 64, SEQ / 64), dim3(256), 0, stream,
                       enc_x, enc_Wi, enc_bi, enc_gi, H, H, 0, H, 3 * H);
    hipLaunchKernelGGL(gemm_nt_kernel, dim3(SEQ / 64, SEQ / 64), dim3(256), 0, stream,
                       dec_e, attn_W, attn_b, attn_e, H, H, 0, 2 * H, SEQ);
    hipLaunchKernelGGL(gemm_nt_kernel, dim3(H / 64, SEQ / 64), dim3(256), 0, stream,
                       dec_e, comb_W, comb_b, comb_pre, H, H, 0, 2 * H, H);

    // phase 2: encoder recurrence
    {
        void* args[] = {(void*)&enc_Wh, (void*)&enc_bh, (void*)&enc_gi,
                        (void*)&h_slots, (void*)&encH};
        hipLaunchCooperativeKernel((void*)enc_rnn_kernel, dim3(256), dim3(256),
                                   args, 0, stream);
    }

    // phase 2.5: M = comb_W[:,H:] @ encH^T
    hipLaunchKernelGGL(gemm_nt_kernel, dim3(SEQ / 64, H / 64), dim3(256), 0, stream,
                       comb_W, encH, (const float*)nullptr, Mmat, H, 2 * H, H, H, SEQ);

    // phase 3: decoder recurrence
    {
        void* args[] = {(void*)&attn_W, (void*)&attn_e, (void*)&Mmat, (void*)&comb_pre,
                        (void*)&dec_Wi, (void*)&dec_Wh, (void*)&dec_bi, (void*)&dec_bh,
                        (void*)&h_slots, (void*)&score_slots, (void*)&c_slots,
                        (void*)&hs_dec};
        hipLaunchCooperativeKernel((void*)dec_rnn_kernel, dim3(256), dim3(256),
                                   args, 0, stream);
    }

    // phase 4: logits = hs_dec @ out_W^T + out_b
    hipLaunchKernelGGL(gemm_nt_kernel, dim3(VOUT / 64, SEQ / 64), dim3(256), 0, stream,
                       hs_dec, out_W, out_b, logits, H, H, 0, H, VOUT);

    // phase 5: NLL + total
    hipLaunchKernelGGL(nll_kernel, dim3(SEQ), dim3(256), 0, stream,
                       logits, target_ids, nll);
    hipLaunchKernelGGL(sum_kernel, dim3(1), dim3(256), 0, stream, nll, out);
}